// Round 6
// baseline (286.640 us; speedup 1.0000x reference)
//
#include <hip/hip_runtime.h>
#include <math.h>

typedef __bf16 bf16x8 __attribute__((ext_vector_type(8)));
typedef float f32x4 __attribute__((ext_vector_type(4)));

__device__ __forceinline__ unsigned short f2bf(float f) {
  unsigned int u = __builtin_bit_cast(unsigned int, f);
  u += 0x7fffu + ((u >> 16) & 1u);
  return (unsigned short)(u >> 16);
}
__device__ __forceinline__ unsigned int pack2bf(float a, float b) {
  return (unsigned int)f2bf(a) | ((unsigned int)f2bf(b) << 16);
}

// ---------- bf16 MFMA GEMM + sigmoid + avgpool2 (fp32->bf16 staged inline) ----------
#define GK_PADK 40
template <int WFP32, int XFP32>
__global__ __launch_bounds__(256) void gemm_mfma_sig_pool(
    const void* __restrict__ Wv, const float* __restrict__ bias,
    const void* __restrict__ Xv, void* __restrict__ Y,
    int K, int Np, int out_bf16) {
  __shared__ unsigned short Wt[64][GK_PADK];
  __shared__ unsigned short Xt[64][GK_PADK];
  const int tid = threadIdx.x;
  const int i_base = blockIdx.x * 64;
  const int b_base = blockIdx.y * 64;
  const int srow = tid >> 2, sseg = tid & 3;
  const int wv = tid >> 6, lane = tid & 63;
  const int wn = wv & 1, wb = wv >> 1;
  const int L15 = lane & 15, q = lane >> 4;

  f32x4 acc[2][2] = {};
  for (int k0 = 0; k0 < K; k0 += 32) {
    if (WFP32) {
      const float* Wf = (const float*)Wv;
      const float4 a = *(const float4*)&Wf[(size_t)(i_base + srow) * K + k0 + sseg * 8];
      const float4 b = *(const float4*)&Wf[(size_t)(i_base + srow) * K + k0 + sseg * 8 + 4];
      uint4 p = { pack2bf(a.x, a.y), pack2bf(a.z, a.w), pack2bf(b.x, b.y), pack2bf(b.z, b.w) };
      *(uint4*)&Wt[srow][sseg * 8] = p;
    } else {
      *(uint4*)&Wt[srow][sseg * 8] =
          *(const uint4*)&((const unsigned short*)Wv)[(size_t)(i_base + srow) * K + k0 + sseg * 8];
    }
    if (XFP32) {
      const float* Xf = (const float*)Xv;
      const float4 a = *(const float4*)&Xf[(size_t)(b_base + srow) * K + k0 + sseg * 8];
      const float4 b = *(const float4*)&Xf[(size_t)(b_base + srow) * K + k0 + sseg * 8 + 4];
      uint4 p = { pack2bf(a.x, a.y), pack2bf(a.z, a.w), pack2bf(b.x, b.y), pack2bf(b.z, b.w) };
      *(uint4*)&Xt[srow][sseg * 8] = p;
    } else {
      *(uint4*)&Xt[srow][sseg * 8] =
          *(const uint4*)&((const unsigned short*)Xv)[(size_t)(b_base + srow) * K + k0 + sseg * 8];
    }
    __syncthreads();
    bf16x8 a0 = *(const bf16x8*)&Wt[wn * 32 + L15][q * 8];
    bf16x8 a1 = *(const bf16x8*)&Wt[wn * 32 + 16 + L15][q * 8];
    bf16x8 b0 = *(const bf16x8*)&Xt[wb * 32 + L15][q * 8];
    bf16x8 b1 = *(const bf16x8*)&Xt[wb * 32 + 16 + L15][q * 8];
    acc[0][0] = __builtin_amdgcn_mfma_f32_16x16x32_bf16(a0, b0, acc[0][0], 0, 0, 0);
    acc[0][1] = __builtin_amdgcn_mfma_f32_16x16x32_bf16(a0, b1, acc[0][1], 0, 0, 0);
    acc[1][0] = __builtin_amdgcn_mfma_f32_16x16x32_bf16(a1, b0, acc[1][0], 0, 0, 0);
    acc[1][1] = __builtin_amdgcn_mfma_f32_16x16x32_bf16(a1, b1, acc[1][1], 0, 0, 0);
    __syncthreads();
  }

  const int nb0 = i_base + wn * 32;
  const int bc0 = b_base + wb * 32 + L15;
#pragma unroll
  for (int mg = 0; mg < 2; mg++) {
    const int nrow = nb0 + mg * 16 + q * 4;
    const float bi0 = bias[nrow], bi1 = bias[nrow + 1];
    const float bi2 = bias[nrow + 2], bi3 = bias[nrow + 3];
#pragma unroll
    for (int bg = 0; bg < 2; bg++) {
      const int b = bc0 + bg * 16;
      f32x4 A = acc[mg][bg];
      const float a0 = __builtin_amdgcn_rcpf(1.f + __expf(-(A[0] + bi0)));
      const float a1 = __builtin_amdgcn_rcpf(1.f + __expf(-(A[1] + bi1)));
      const float a2 = __builtin_amdgcn_rcpf(1.f + __expf(-(A[2] + bi2)));
      const float a3 = __builtin_amdgcn_rcpf(1.f + __expf(-(A[3] + bi3)));
      const float p0 = 0.5f * (a0 + a1), p1 = 0.5f * (a2 + a3);
      const int pidx = nrow >> 1;  // even
      if (out_bf16) {
        *(unsigned int*)&((unsigned short*)Y)[(size_t)b * Np + pidx] = pack2bf(p0, p1);
      } else {
        *(float2*)&((float*)Y)[(size_t)b * Np + pidx] = make_float2(p0, p1);
      }
    }
  }
}

// ---------- LSTM tail ----------
// 832 threads. Lane (r=t>>3, gp=(t>>2)&1, kq=t&3) owns TWO gate rows
// (gp=0 -> i,f ; gp=1 -> g,o) over k-quarter [25kq,25kq+25) = 50 fp32
// weights, small enough to stay resident in the compiler's 64-VGPR budget.
// h stored in LDS as 4 chunks at stride 36 floats (16B-aligned, banks offset
// by 4 per quarter -> conflict-free b128 broadcasts). Quad butterfly (DPP
// 0xB1+0x4E) over kq completes the 100-dots; kq==1 lanes activate gate A,
// kq==2 activate gate B into zs[]; t<100 lanes do the c/h update.
#define HID 100
#define TSTEPS 256
#define LTHREADS 832
#define HSTRIDE 36

__device__ __forceinline__ float qx1(float x) {
  int v = __builtin_amdgcn_mov_dpp(__builtin_bit_cast(int, x), 0xB1, 0xf, 0xf, true);
  return x + __builtin_bit_cast(float, v);
}
__device__ __forceinline__ float qx2(float x) {
  int v = __builtin_amdgcn_mov_dpp(__builtin_bit_cast(int, x), 0x4E, 0xf, 0xf, true);
  return x + __builtin_bit_cast(float, v);
}

__global__ __launch_bounds__(LTHREADS) __attribute__((amdgpu_waves_per_eu(1, 4)))
void lstm_tail(
    const float* __restrict__ X, const float* __restrict__ Wih,
    const float* __restrict__ Whh, const float* __restrict__ bgates,
    const float* __restrict__ Wout, const float* __restrict__ bout,
    float* __restrict__ out) {
  const int bat = blockIdx.x;
  const int t = threadIdx.x;
  const int r = t >> 3;            // hidden row 0..103 (valid < 100)
  const int gp = (t >> 2) & 1;     // gate pair: 0 -> (i,f), 1 -> (g,o)
  const int kq = t & 3;            // k quarter
  const bool wvalid = (r < HID);
  const int rr = wvalid ? r : 0;
  const int rowA = gp * 200 + rr;  // i (gp=0) or g (gp=1)
  const int rowB = rowA + 100;     // f (gp=0) or o (gp=1)
  const int koff = 25 * kq;

  __shared__ __align__(16) float hbuf[2][160];
  __shared__ float zs[400];
  __shared__ float xrow[TSTEPS];
  __shared__ float red[HID];

  for (int i = t; i < TSTEPS; i += LTHREADS) xrow[i] = X[(size_t)bat * TSTEPS + i];

  const float* WA = &Whh[(size_t)rowA * HID + koff];
  const float* WB = &Whh[(size_t)rowB * HID + koff];
#define DECLW(P) float4 P##_0, P##_1, P##_2, P##_3, P##_4, P##_5; float P##_6;
  DECLW(wa) DECLW(wb)
#undef DECLW
#define LW(P, B)                                      \
  P##_0 = make_float4(B[0],  B[1],  B[2],  B[3]);     \
  P##_1 = make_float4(B[4],  B[5],  B[6],  B[7]);     \
  P##_2 = make_float4(B[8],  B[9],  B[10], B[11]);    \
  P##_3 = make_float4(B[12], B[13], B[14], B[15]);    \
  P##_4 = make_float4(B[16], B[17], B[18], B[19]);    \
  P##_5 = make_float4(B[20], B[21], B[22], B[23]);    \
  P##_6 = B[24];
  LW(wa, WA) LW(wb, WB)
#undef LW

  // activation duty: kq==1 -> gate A, kq==2 -> gate B
  const bool doact = wvalid && (kq == 1 || kq == 2);
  const int wrow = (kq == 1) ? rowA : rowB;
  const float u_  = Wih[wrow];
  const float bz_ = bgates[wrow];
  const bool is_tanh = (kq == 1 && gp == 1);  // only the g gate
  const float ka = is_tanh ? 2.f : 1.f;
  const float ma = is_tanh ? 2.f : 1.f;
  const float da = is_tanh ? -1.f : 0.f;

  if (t < 160) { hbuf[0][t] = 0.f; hbuf[1][t] = 0.f; }
  float c = 0.f;
  __syncthreads();

  for (int step = 0; step < TSTEPS; step++) {
    const int cur = step & 1;
    const float* hq = &hbuf[cur][kq * HSTRIDE];
    float za = 0.f, zb = 0.f;
#define DG(OFF, A, B)                                        \
    { const float4 h4 = *(const float4*)&hq[OFF];            \
      za = fmaf(A.x, h4.x, za); zb = fmaf(B.x, h4.x, zb);    \
      za = fmaf(A.y, h4.y, za); zb = fmaf(B.y, h4.y, zb);    \
      za = fmaf(A.z, h4.z, za); zb = fmaf(B.z, h4.z, zb);    \
      za = fmaf(A.w, h4.w, za); zb = fmaf(B.w, h4.w, zb); }
    DG(0,  wa_0, wb_0)
    DG(4,  wa_1, wb_1)
    DG(8,  wa_2, wb_2)
    DG(12, wa_3, wb_3)
    DG(16, wa_4, wb_4)
    DG(20, wa_5, wb_5)
    { const float h1 = hq[24];
      za = fmaf(wa_6, h1, za); zb = fmaf(wb_6, h1, zb); }
#undef DG
    // quad butterfly over kq: all 4 lanes get the full 100-k sums
    za = qx2(qx1(za));
    zb = qx2(qx1(zb));
    if (doact) {
      const float zsel = (kq == 1) ? za : zb;
      const float zfull = fmaf(u_, xrow[step], zsel + bz_);
      zs[wrow] = ma * __builtin_amdgcn_rcpf(1.f + __expf(-ka * zfull)) + da;
    }
    __syncthreads();
    if (t < HID) {
      const float ai = zs[t], af = zs[t + 100], ag = zs[t + 200], ao = zs[t + 300];
      c = fmaf(af, c, ai * ag);
      const float th = 2.f * __builtin_amdgcn_rcpf(1.f + __expf(-2.f * c)) - 1.f;
      hbuf[cur ^ 1][(t / 25) * HSTRIDE + (t % 25)] = ao * th;
    }
    __syncthreads();
  }

  // final h is in hbuf[0] (256 steps, even): out[bat] = dot(h, Wout) + bout
  if (t < HID) red[t] = hbuf[0][(t / 25) * HSTRIDE + (t % 25)] * Wout[t];
  __syncthreads();
  if (t == 0) {
    float s = 0.f;
#pragma unroll
    for (int k = 0; k < HID; k++) s += red[k];
    out[bat] = s + bout[0];
  }
}

// ---------- launch ----------
extern "C" void kernel_launch(void* const* d_in, const int* in_sizes, int n_in,
                              void* d_out, int out_size, void* d_ws, size_t ws_size,
                              hipStream_t stream) {
  const float* x    = (const float*)d_in[0];   // (256,1024)
  const float* W1L  = (const float*)d_in[3];   // (1024,1024)
  const float* b1L  = (const float*)d_in[4];
  const float* W2L  = (const float*)d_in[7];   // (512,512)
  const float* b2L  = (const float*)d_in[8];
  const float* Wih3 = (const float*)d_in[15];  // (400,1)
  const float* Whh3 = (const float*)d_in[16];  // (400,100)
  const float* b3   = (const float*)d_in[17];  // (400,)
  const float* Wout = (const float*)d_in[18];  // (1,100)
  const float* bout = (const float*)d_in[19];  // (1,)
  float* out = (float*)d_out;                  // (256,)

  unsigned short* xl1b = (unsigned short*)d_ws;     // 256x512 bf16
  float* xl2 = (float*)(xl1b + (size_t)256 * 512);  // 256x256 f32

  gemm_mfma_sig_pool<1, 1><<<dim3(16, 4), 256, 0, stream>>>(W1L, b1L, x, xl1b, 1024, 512, 1);
  gemm_mfma_sig_pool<1, 0><<<dim3(8, 4), 256, 0, stream>>>(W2L, b2L, xl1b, xl2, 512, 256, 0);
  lstm_tail<<<256, LTHREADS, 0, stream>>>(xl2, Wih3, Whh3, b3, Wout, bout, out);
}

// Round 7
// 280.071 us; speedup vs baseline: 1.0235x; 1.0235x over previous
//
#include <hip/hip_runtime.h>
#include <math.h>

typedef __bf16 bf16x8 __attribute__((ext_vector_type(8)));
typedef float f32x4 __attribute__((ext_vector_type(4)));

__device__ __forceinline__ unsigned short f2bf(float f) {
  unsigned int u = __builtin_bit_cast(unsigned int, f);
  u += 0x7fffu + ((u >> 16) & 1u);
  return (unsigned short)(u >> 16);
}
__device__ __forceinline__ unsigned int pack2bf(float a, float b) {
  return (unsigned int)f2bf(a) | ((unsigned int)f2bf(b) << 16);
}

// ---------- bf16 MFMA GEMM + sigmoid + avgpool2 (fp32->bf16 staged inline) ----------
#define GK_PADK 40
template <int WFP32, int XFP32>
__global__ __launch_bounds__(256) void gemm_mfma_sig_pool(
    const void* __restrict__ Wv, const float* __restrict__ bias,
    const void* __restrict__ Xv, void* __restrict__ Y,
    int K, int Np, int out_bf16) {
  __shared__ unsigned short Wt[64][GK_PADK];
  __shared__ unsigned short Xt[64][GK_PADK];
  const int tid = threadIdx.x;
  const int i_base = blockIdx.x * 64;
  const int b_base = blockIdx.y * 64;
  const int srow = tid >> 2, sseg = tid & 3;
  const int wv = tid >> 6, lane = tid & 63;
  const int wn = wv & 1, wb = wv >> 1;
  const int L15 = lane & 15, q = lane >> 4;

  f32x4 acc[2][2] = {};
  for (int k0 = 0; k0 < K; k0 += 32) {
    if (WFP32) {
      const float* Wf = (const float*)Wv;
      const float4 a = *(const float4*)&Wf[(size_t)(i_base + srow) * K + k0 + sseg * 8];
      const float4 b = *(const float4*)&Wf[(size_t)(i_base + srow) * K + k0 + sseg * 8 + 4];
      uint4 p = { pack2bf(a.x, a.y), pack2bf(a.z, a.w), pack2bf(b.x, b.y), pack2bf(b.z, b.w) };
      *(uint4*)&Wt[srow][sseg * 8] = p;
    } else {
      *(uint4*)&Wt[srow][sseg * 8] =
          *(const uint4*)&((const unsigned short*)Wv)[(size_t)(i_base + srow) * K + k0 + sseg * 8];
    }
    if (XFP32) {
      const float* Xf = (const float*)Xv;
      const float4 a = *(const float4*)&Xf[(size_t)(b_base + srow) * K + k0 + sseg * 8];
      const float4 b = *(const float4*)&Xf[(size_t)(b_base + srow) * K + k0 + sseg * 8 + 4];
      uint4 p = { pack2bf(a.x, a.y), pack2bf(a.z, a.w), pack2bf(b.x, b.y), pack2bf(b.z, b.w) };
      *(uint4*)&Xt[srow][sseg * 8] = p;
    } else {
      *(uint4*)&Xt[srow][sseg * 8] =
          *(const uint4*)&((const unsigned short*)Xv)[(size_t)(b_base + srow) * K + k0 + sseg * 8];
    }
    __syncthreads();
    bf16x8 a0 = *(const bf16x8*)&Wt[wn * 32 + L15][q * 8];
    bf16x8 a1 = *(const bf16x8*)&Wt[wn * 32 + 16 + L15][q * 8];
    bf16x8 b0 = *(const bf16x8*)&Xt[wb * 32 + L15][q * 8];
    bf16x8 b1 = *(const bf16x8*)&Xt[wb * 32 + 16 + L15][q * 8];
    acc[0][0] = __builtin_amdgcn_mfma_f32_16x16x32_bf16(a0, b0, acc[0][0], 0, 0, 0);
    acc[0][1] = __builtin_amdgcn_mfma_f32_16x16x32_bf16(a0, b1, acc[0][1], 0, 0, 0);
    acc[1][0] = __builtin_amdgcn_mfma_f32_16x16x32_bf16(a1, b0, acc[1][0], 0, 0, 0);
    acc[1][1] = __builtin_amdgcn_mfma_f32_16x16x32_bf16(a1, b1, acc[1][1], 0, 0, 0);
    __syncthreads();
  }

  const int nb0 = i_base + wn * 32;
  const int bc0 = b_base + wb * 32 + L15;
#pragma unroll
  for (int mg = 0; mg < 2; mg++) {
    const int nrow = nb0 + mg * 16 + q * 4;
    const float bi0 = bias[nrow], bi1 = bias[nrow + 1];
    const float bi2 = bias[nrow + 2], bi3 = bias[nrow + 3];
#pragma unroll
    for (int bg = 0; bg < 2; bg++) {
      const int b = bc0 + bg * 16;
      f32x4 A = acc[mg][bg];
      const float a0 = __builtin_amdgcn_rcpf(1.f + __expf(-(A[0] + bi0)));
      const float a1 = __builtin_amdgcn_rcpf(1.f + __expf(-(A[1] + bi1)));
      const float a2 = __builtin_amdgcn_rcpf(1.f + __expf(-(A[2] + bi2)));
      const float a3 = __builtin_amdgcn_rcpf(1.f + __expf(-(A[3] + bi3)));
      const float p0 = 0.5f * (a0 + a1), p1 = 0.5f * (a2 + a3);
      const int pidx = nrow >> 1;  // even
      if (out_bf16) {
        *(unsigned int*)&((unsigned short*)Y)[(size_t)b * Np + pidx] = pack2bf(p0, p1);
      } else {
        *(float2*)&((float*)Y)[(size_t)b * Np + pidx] = make_float2(p0, p1);
      }
    }
  }
}

// ---------- LSTM tail ----------
// Lane (r=t>>2, kq=t&3) owns all 4 gates of hidden row r over k-quarter
// [25kq, 25kq+25) -> 100 weights per lane. An empty asm volatile "+v" touch
// INSIDE the step loop makes every weight value loop-carried and opaque:
// LLVM can neither rematerialize the global load inside the loop (the R5/R6
// failure: VGPR=36-64, weights re-streamed from L1 every step, ~1350 cyc/step)
// nor spill it cheaply -> real VGPR residency. 448 thr = 7 waves ->
// waves_per_eu(1,2) grants a 256-VGPR budget. h in LDS as 4 chunks at
// stride 36 floats (16B-aligned, conflict-free: validated R6, conflicts
// 1.38e7 -> 2e5). Quad butterfly (DPP 0xB1+0x4E) completes the 100-dots;
// activations + c/h replicated per quad; one barrier per step.
#define HID 100
#define TSTEPS 256
#define HSTRIDE 36

__device__ __forceinline__ float qx1(float x) {
  int v = __builtin_amdgcn_mov_dpp(__builtin_bit_cast(int, x), 0xB1, 0xf, 0xf, true);
  return x + __builtin_bit_cast(float, v);
}
__device__ __forceinline__ float qx2(float x) {
  int v = __builtin_amdgcn_mov_dpp(__builtin_bit_cast(int, x), 0x4E, 0xf, 0xf, true);
  return x + __builtin_bit_cast(float, v);
}

__global__ __launch_bounds__(448) __attribute__((amdgpu_waves_per_eu(1, 2)))
void lstm_tail(
    const float* __restrict__ X, const float* __restrict__ Wih,
    const float* __restrict__ Whh, const float* __restrict__ bgates,
    const float* __restrict__ Wout, const float* __restrict__ bout,
    float* __restrict__ out) {
  const int bat = blockIdx.x;
  const int t = threadIdx.x;
  const int r = t >> 2;        // hidden row (valid < 100)
  const int kq = t & 3;        // k quarter
  const int koff = 25 * kq;
  const bool valid = (r < HID);
  const int rr = valid ? r : 0;
  __shared__ __align__(16) float hbuf[2][160];
  __shared__ float xrow[TSTEPS];
  __shared__ float red[HID];

  for (int i = t; i < TSTEPS; i += 448) xrow[i] = X[(size_t)bat * TSTEPS + i];

  const float* Wr0 = &Whh[(size_t)(0 * HID + rr) * HID + koff];
  const float* Wr1 = &Whh[(size_t)(1 * HID + rr) * HID + koff];
  const float* Wr2 = &Whh[(size_t)(2 * HID + rr) * HID + koff];
  const float* Wr3 = &Whh[(size_t)(3 * HID + rr) * HID + koff];

#define DECLW(P) f32x4 P##_0, P##_1, P##_2, P##_3, P##_4, P##_5; float P##_6;
  DECLW(wi) DECLW(wf) DECLW(wg) DECLW(wo)
#undef DECLW
#define LW(P, B)                                               \
  P##_0 = (f32x4){B[0],  B[1],  B[2],  B[3]};                  \
  P##_1 = (f32x4){B[4],  B[5],  B[6],  B[7]};                  \
  P##_2 = (f32x4){B[8],  B[9],  B[10], B[11]};                 \
  P##_3 = (f32x4){B[12], B[13], B[14], B[15]};                 \
  P##_4 = (f32x4){B[16], B[17], B[18], B[19]};                 \
  P##_5 = (f32x4){B[20], B[21], B[22], B[23]};                 \
  P##_6 = B[24];
  LW(wi, Wr0) LW(wf, Wr1) LW(wg, Wr2) LW(wo, Wr3)
#undef LW

  const float bi_ = bgates[0 * HID + rr], bf_ = bgates[1 * HID + rr];
  const float bg_ = bgates[2 * HID + rr], bo_ = bgates[3 * HID + rr];
  const float ui = Wih[0 * HID + rr], uf = Wih[1 * HID + rr];
  const float ug = Wih[2 * HID + rr], uo = Wih[3 * HID + rr];

  const int hpos = (rr / 25) * HSTRIDE + (rr % 25);  // conflict-free chunk slot

  if (t < 160) { hbuf[0][t] = 0.f; hbuf[1][t] = 0.f; }
  float c = 0.f;
  __syncthreads();

  for (int step = 0; step < TSTEPS; step++) {
    // Loop-carried opaque touch: forbids remat of the weight loads inside the
    // loop and makes spilling cost 2 scratch ops/iter -> RA keeps them in VGPRs.
#define TOUCH(P) asm volatile("" : "+v"(P##_0), "+v"(P##_1), "+v"(P##_2), \
                                   "+v"(P##_3), "+v"(P##_4), "+v"(P##_5), "+v"(P##_6))
    TOUCH(wi); TOUCH(wf); TOUCH(wg); TOUCH(wo);
#undef TOUCH
    const float* hq = &hbuf[step & 1][kq * HSTRIDE];
    float z0 = 0.f, z1 = 0.f, z2 = 0.f, z3 = 0.f;
#define G4(OFF, WI, WF, WG, WO)                                                  \
    { const float4 h4 = *(const float4*)&hq[OFF];                                \
      z0 = fmaf(WI[0], h4.x, z0); z1 = fmaf(WF[0], h4.x, z1);                    \
      z2 = fmaf(WG[0], h4.x, z2); z3 = fmaf(WO[0], h4.x, z3);                    \
      z0 = fmaf(WI[1], h4.y, z0); z1 = fmaf(WF[1], h4.y, z1);                    \
      z2 = fmaf(WG[1], h4.y, z2); z3 = fmaf(WO[1], h4.y, z3);                    \
      z0 = fmaf(WI[2], h4.z, z0); z1 = fmaf(WF[2], h4.z, z1);                    \
      z2 = fmaf(WG[2], h4.z, z2); z3 = fmaf(WO[2], h4.z, z3);                    \
      z0 = fmaf(WI[3], h4.w, z0); z1 = fmaf(WF[3], h4.w, z1);                    \
      z2 = fmaf(WG[3], h4.w, z2); z3 = fmaf(WO[3], h4.w, z3); }
    G4(0,  wi_0, wf_0, wg_0, wo_0)
    G4(4,  wi_1, wf_1, wg_1, wo_1)
    G4(8,  wi_2, wf_2, wg_2, wo_2)
    G4(12, wi_3, wf_3, wg_3, wo_3)
    G4(16, wi_4, wf_4, wg_4, wo_4)
    G4(20, wi_5, wf_5, wg_5, wo_5)
    { const float h1 = hq[24];
      z0 = fmaf(wi_6, h1, z0); z1 = fmaf(wf_6, h1, z1);
      z2 = fmaf(wg_6, h1, z2); z3 = fmaf(wo_6, h1, z3); }
#undef G4
    // quad butterfly: every lane of the quad gets the full 100-k sums
    z0 = qx2(qx1(z0)); z1 = qx2(qx1(z1)); z2 = qx2(qx1(z2)); z3 = qx2(qx1(z3));

    const float xt = xrow[step];
    const float zi = fmaf(ui, xt, z0 + bi_);
    const float zf = fmaf(uf, xt, z1 + bf_);
    const float zg = fmaf(ug, xt, z2 + bg_);
    const float zo = fmaf(uo, xt, z3 + bo_);
    const float ai = __builtin_amdgcn_rcpf(1.f + __expf(-zi));
    const float af = __builtin_amdgcn_rcpf(1.f + __expf(-zf));
    const float ag = 2.f * __builtin_amdgcn_rcpf(1.f + __expf(-2.f * zg)) - 1.f;
    const float ao = __builtin_amdgcn_rcpf(1.f + __expf(-zo));
    c = fmaf(af, c, ai * ag);
    const float th = 2.f * __builtin_amdgcn_rcpf(1.f + __expf(-2.f * c)) - 1.f;
    if (kq == 0 && valid) hbuf[(step & 1) ^ 1][hpos] = ao * th;
    __syncthreads();
  }

  if (t < HID) red[t] = hbuf[0][(t / 25) * HSTRIDE + (t % 25)] * Wout[t];
  __syncthreads();
  if (t == 0) {
    float s = 0.f;
#pragma unroll
    for (int k = 0; k < HID; k++) s += red[k];
    out[bat] = s + bout[0];
  }
}

// ---------- launch ----------
extern "C" void kernel_launch(void* const* d_in, const int* in_sizes, int n_in,
                              void* d_out, int out_size, void* d_ws, size_t ws_size,
                              hipStream_t stream) {
  const float* x    = (const float*)d_in[0];   // (256,1024)
  const float* W1L  = (const float*)d_in[3];   // (1024,1024)
  const float* b1L  = (const float*)d_in[4];
  const float* W2L  = (const float*)d_in[7];   // (512,512)
  const float* b2L  = (const float*)d_in[8];
  const float* Wih3 = (const float*)d_in[15];  // (400,1)
  const float* Whh3 = (const float*)d_in[16];  // (400,100)
  const float* b3   = (const float*)d_in[17];  // (400,)
  const float* Wout = (const float*)d_in[18];  // (1,100)
  const float* bout = (const float*)d_in[19];  // (1,)
  float* out = (float*)d_out;                  // (256,)

  unsigned short* xl1b = (unsigned short*)d_ws;     // 256x512 bf16
  float* xl2 = (float*)(xl1b + (size_t)256 * 512);  // 256x256 f32

  gemm_mfma_sig_pool<1, 1><<<dim3(16, 4), 256, 0, stream>>>(W1L, b1L, x, xl1b, 1024, 512, 1);
  gemm_mfma_sig_pool<1, 0><<<dim3(8, 4), 256, 0, stream>>>(W2L, b2L, xl1b, xl2, 512, 256, 0);
  lstm_tail<<<256, 448, 0, stream>>>(xl2, Wih3, Whh3, b3, Wout, bout, out);
}